// Round 2
// baseline (115.642 us; speedup 1.0000x reference)
//
#include <hip/hip_runtime.h>

// Problem constants
#define B 64
#define D 25000
#define K 16
#define H 128
#define E 256
#define Z 32
#define DTILE 16
#define NT_TILES 1563            // ceil(25000/16)
#define TILES_PER_BLK 2
#define NPB 782                  // ceil(1563/2) persistent blocks, contiguous tile chunks
#define NREP 8                   // one replica per XCD
#define XSTR 68                  // padded LDS stride (halves) for x/mask tiles: conflict-free transpose writes

#define REP_BYTES (NREP * B * K * 4)   // 32768 B — only workspace needed now

typedef __attribute__((ext_vector_type(8))) _Float16 half8;
typedef __attribute__((ext_vector_type(4))) _Float16 hv4;
typedef __attribute__((ext_vector_type(2))) _Float16 hv2;
typedef __attribute__((ext_vector_type(4))) float f32x4;

// Fused main: persistent blocks, each owns TILES_PER_BLK contiguous d-tiles.
// Per tile: stage x/mask direct from global (f32 -> fp16, LDS transpose),
// G tile via MFMA (B-fragments of extended W1 built per-lane from global),
// inner loop h1 = relu(x*w0 + G) -> h2 MFMA -> masked fp32 accumulation in regs.
// One atomic set per thread at the very end (0.8M atomics vs 2.56M before).
__global__ __launch_bounds__(256) void main_kernel(
    const float* __restrict__ x, const int* __restrict__ mask,
    const float* __restrict__ feat_emb, const float* __restrict__ feat_bias,
    const float* __restrict__ W1, const float* __restrict__ b1,
    const float* __restrict__ W2, const float* __restrict__ b2,
    float* __restrict__ rep)
{
    __shared__ __align__(16) _Float16 sGh[2][DTILE * H];     // 2 x 4 KB
    __shared__ __align__(16) _Float16 sXh[2][DTILE * XSTR];  // 2 x 2.125 KB
    __shared__ __align__(16) _Float16 sMh[2][DTILE * XSTR];

    const int t    = threadIdx.x;
    const int lane = t & 63;
    const int wv   = t >> 6;
    const int g    = lane >> 4;
    const int n    = lane & 15;

    // ---- per-block constant fragments (weights are L1/L2-resident: W1 9KB, W2 8KB) ----
    half8 Bf[4];                      // W2 fragments for h2 MFMA
    #pragma unroll
    for (int s = 0; s < 4; ++s) {
        union { half8 v; _Float16 e[8]; } u;
        #pragma unroll
        for (int j = 0; j < 8; ++j)
            u.e[j] = (_Float16)W2[(s * 32 + g * 8 + j) * K + n];
        Bf[s] = u.v;
    }
    hv2 w0h[4][4];                    // W1 row 0 (x-coefficient), packed fp16 pairs
    #pragma unroll
    for (int s = 0; s < 4; ++s) {
        const float4* wp = (const float4*)&W1[s * 32 + g * 8];
        float4 a0 = wp[0], a1 = wp[1];
        w0h[s][0] = (hv2){(_Float16)a0.x, (_Float16)a0.y};
        w0h[s][1] = (hv2){(_Float16)a0.z, (_Float16)a0.w};
        w0h[s][2] = (hv2){(_Float16)a1.x, (_Float16)a1.y};
        w0h[s][3] = (hv2){(_Float16)a1.z, (_Float16)a1.w};
    }
    half8 bfG[2];                     // extended-W1 B fragments for G MFMA (this wave's two c's)
    #pragma unroll
    for (int cc = 0; cc < 2; ++cc) {
        const int h = (wv * 2 + cc) * 16 + n;
        union { half8 v; _Float16 e[8]; } u;
        #pragma unroll
        for (int j = 0; j < 8; ++j) {
            const int k = g * 8 + j;
            float v;
            if (k < 16)       v = W1[(1 + k) * H + h];
            else if (k == 16) v = W1[17 * H + h];   // feat_bias coefficient row
            else if (k == 17) v = b1[h];            // x 1.0 in A
            else              v = 0.f;
            u.e[j] = (_Float16)v;
        }
        bfG[cc] = u.v;
    }
    const float b2n = b2[n];
    const hv2 zeroh = {(_Float16)0.f, (_Float16)0.f};
    const int moff = wv * 16 + g * 4;
    const int sample = wv * 16 + n;

    const int t0 = blockIdx.x * TILES_PER_BLK;
    const int t1 = min(t0 + TILES_PER_BLK, NT_TILES);

    // stage one 64x16 x/mask tile: coalesced float4/int4 row reads, fp16 transpose into LDS
    auto STAGE = [&](int buf, int tile) {
        const int bb = t >> 2;              // sample row 0..63
        const int dd = (t & 3) * 4;         // 0,4,8,12
        const int dg = tile * DTILE + dd;
        float xv[4], mv[4];
        if (dg + 4 <= D) {
            float4 xx = *(const float4*)&x[(size_t)bb * D + dg];
            int4   mm = *(const int4*)&mask[(size_t)bb * D + dg];
            xv[0] = xx.x; xv[1] = xx.y; xv[2] = xx.z; xv[3] = xx.w;
            mv[0] = (float)mm.x; mv[1] = (float)mm.y; mv[2] = (float)mm.z; mv[3] = (float)mm.w;
        } else {                            // only the final partial tile takes this path
            #pragma unroll
            for (int i = 0; i < 4; ++i) {
                const int dgi = dg + i;
                xv[i] = (dgi < D) ? x[(size_t)bb * D + dgi] : 0.f;
                mv[i] = (dgi < D) ? (float)mask[(size_t)bb * D + dgi] : 0.f;
            }
        }
        #pragma unroll
        for (int i = 0; i < 4; ++i) {
            sXh[buf][(dd + i) * XSTR + bb] = (_Float16)xv[i];
            sMh[buf][(dd + i) * XSTR + bb] = (_Float16)mv[i];
        }
    };

    // G tile: A[m=dd][k] = [feat_emb | feat_bias | 1 | 0], all 16 MFMA rows used now
    auto GCOMP = [&](int buf, int tile) {
        const int dA = min(tile * DTILE + n, D - 1);  // OOB rows give garbage G, killed by mask=0
        union { half8 v; _Float16 e[8]; } af;
        if (g < 2) {
            const float4* fe = (const float4*)&feat_emb[(size_t)dA * K + g * 8];
            float4 u0 = fe[0], u1 = fe[1];
            af.e[0] = (_Float16)u0.x; af.e[1] = (_Float16)u0.y;
            af.e[2] = (_Float16)u0.z; af.e[3] = (_Float16)u0.w;
            af.e[4] = (_Float16)u1.x; af.e[5] = (_Float16)u1.y;
            af.e[6] = (_Float16)u1.z; af.e[7] = (_Float16)u1.w;
        } else if (g == 2) {
            af.e[0] = (_Float16)feat_bias[dA];
            af.e[1] = (_Float16)1.f;
            #pragma unroll
            for (int j = 2; j < 8; ++j) af.e[j] = (_Float16)0.f;
        } else {
            #pragma unroll
            for (int j = 0; j < 8; ++j) af.e[j] = (_Float16)0.f;
        }
        #pragma unroll
        for (int cc = 0; cc < 2; ++cc) {
            f32x4 C = {0.f, 0.f, 0.f, 0.f};
            C = __builtin_amdgcn_mfma_f32_16x16x32_f16(af.v, bfG[cc], C, 0, 0, 0);
            #pragma unroll
            for (int r = 0; r < 4; ++r)
                sGh[buf][(g * 4 + r) * H + (wv * 2 + cc) * 16 + n] = (_Float16)C[r];
        }
    };

    f32x4 cacc = {0.f, 0.f, 0.f, 0.f};

    STAGE(0, t0);
    GCOMP(0, t0);
    __syncthreads();

    int cur = 0;
    for (int tt = t0; tt < t1; ++tt) {
        if (tt + 1 < t1) { STAGE(cur ^ 1, tt + 1); GCOMP(cur ^ 1, tt + 1); }  // overlap next stage

        hv2 xh[DTILE / 2];
        #pragma unroll
        for (int i = 0; i < DTILE / 2; ++i)
            xh[i] = (hv2){sXh[cur][(2 * i) * XSTR + sample],
                          sXh[cur][(2 * i + 1) * XSTR + sample]};
        const _Float16* gb0 = sGh[cur] + g * 8;

        #pragma unroll
        for (int i = 0; i < DTILE / 2; ++i) {
            const int dd0 = 2 * i, dd1 = 2 * i + 1;
            const hv2 xa = {xh[i].x, xh[i].x};
            const hv2 xb = {xh[i].y, xh[i].y};
            f32x4 c1a = {b2n, b2n, b2n, b2n};
            f32x4 c1b = {b2n, b2n, b2n, b2n};
            #pragma unroll
            for (int s = 0; s < 4; ++s) {
                union GA { half8 v; hv2 p[4]; };
                GA ga, gb, A0, A1;
                ga.v = *(const half8*)(gb0 + dd0 * H + s * 32);  // broadcast ds_read_b128
                gb.v = *(const half8*)(gb0 + dd1 * H + s * 32);
                #pragma unroll
                for (int p = 0; p < 4; ++p) {
                    hv2 h0 = __builtin_elementwise_fma(xa, w0h[s][p], ga.p[p]);
                    hv2 h1 = __builtin_elementwise_fma(xb, w0h[s][p], gb.p[p]);
                    A0.p[p] = __builtin_elementwise_max(h0, zeroh);
                    A1.p[p] = __builtin_elementwise_max(h1, zeroh);
                }
                c1a = __builtin_amdgcn_mfma_f32_16x16x32_f16(A0.v, Bf[s], c1a, 0, 0, 0);
                c1b = __builtin_amdgcn_mfma_f32_16x16x32_f16(A1.v, Bf[s], c1b, 0, 0, 0);
            }
            hv4 m0 = *(const hv4*)&sMh[cur][dd0 * XSTR + moff];
            hv4 m1 = *(const hv4*)&sMh[cur][dd1 * XSTR + moff];
            cacc[0] = fmaf((float)m0.x, fmaxf(c1a[0], 0.f), fmaf((float)m1.x, fmaxf(c1b[0], 0.f), cacc[0]));
            cacc[1] = fmaf((float)m0.y, fmaxf(c1a[1], 0.f), fmaf((float)m1.y, fmaxf(c1b[1], 0.f), cacc[1]));
            cacc[2] = fmaf((float)m0.z, fmaxf(c1a[2], 0.f), fmaf((float)m1.z, fmaxf(c1b[2], 0.f), cacc[2]));
            cacc[3] = fmaf((float)m0.w, fmaxf(c1a[3], 0.f), fmaf((float)m1.w, fmaxf(c1b[3], 0.f), cacc[3]));
        }
        __syncthreads();
        cur ^= 1;
    }

    // XCD-local replica atomics, once per block
    float* crep = rep + (size_t)(blockIdx.x & (NREP - 1)) * (B * K);
    #pragma unroll
    for (int r = 0; r < 4; ++r)
        atomicAdd(&crep[(moff + r) * K + n], cacc[r]);
}

// enc: reduce NREP replicas -> c[b], then 16->256->64 MLP. one block per sample.
__global__ __launch_bounds__(256) void partial_enc_kernel(
    const float* __restrict__ rep, const float* __restrict__ We1,
    const float* __restrict__ be1, const float* __restrict__ We2,
    const float* __restrict__ be2, float* __restrict__ out)
{
    const int b = blockIdx.x;
    const int t = threadIdx.x;
    __shared__ float sc[K];
    __shared__ float st1[E];
    __shared__ float red[256];

    {
        const int k = t & 15, grp = t >> 4;
        red[t] = (grp < NREP) ? rep[grp * (B * K) + b * K + k] : 0.f;
    }
    __syncthreads();
    if (t < K) {
        float s2 = 0.f;
        #pragma unroll
        for (int q = 0; q < 16; ++q) s2 += red[q * 16 + t];
        sc[t] = s2;
    }
    __syncthreads();

    {
        float acc = be1[t];
        #pragma unroll
        for (int k = 0; k < K; ++k)
            acc = fmaf(sc[k], We1[k * E + t], acc);
        st1[t] = fmaxf(acc, 0.f);
    }
    __syncthreads();

    const int j = t & 63, seg = t >> 6;
    float acc = 0.f;
    #pragma unroll 4
    for (int e = seg * 64; e < seg * 64 + 64; ++e)
        acc = fmaf(st1[e], We2[e * 64 + j], acc);
    red[t] = acc;
    __syncthreads();

    if (t < 64) {
        float v = red[j] + red[64 + j] + red[128 + j] + red[192 + j] + be2[j];
        if (j < Z) out[b * Z + j] = v;                 // mu
        else       out[B * Z + b * Z + (j - Z)] = v;   // logvar
    }
}

extern "C" void kernel_launch(void* const* d_in, const int* in_sizes, int n_in,
                              void* d_out, int out_size, void* d_ws, size_t ws_size,
                              hipStream_t stream) {
    const float* x         = (const float*)d_in[0];
    const int*   mask      = (const int*)  d_in[1];
    const float* feat_emb  = (const float*)d_in[2];
    const float* feat_bias = (const float*)d_in[3];
    const float* W1        = (const float*)d_in[4];
    const float* b1        = (const float*)d_in[5];
    const float* W2        = (const float*)d_in[6];
    const float* b2        = (const float*)d_in[7];
    const float* We1       = (const float*)d_in[8];
    const float* be1       = (const float*)d_in[9];
    const float* We2       = (const float*)d_in[10];
    const float* be2       = (const float*)d_in[11];

    float* rep = (float*)d_ws;

    hipMemsetAsync(rep, 0, REP_BYTES, stream);   // capture-safe, 32 KB
    main_kernel<<<NPB, 256, 0, stream>>>(
        x, mask, feat_emb, feat_bias, W1, b1, W2, b2, rep);
    partial_enc_kernel<<<B, 256, 0, stream>>>(
        rep, We1, be1, We2, be2, (float*)d_out);
}

// Round 3
// 112.126 us; speedup vs baseline: 1.0314x; 1.0314x over previous
//
#include <hip/hip_runtime.h>

// Problem constants
#define B 64
#define D 25000
#define K 16
#define H 128
#define E 256
#define Z 32
#define DTILE 16
#define NT_TILES ((D + DTILE - 1) / DTILE)   // 1563
#define NPB 512                  // grid-stride blocks: 2/CU, 3-4 tiles each
#define XSTR 68                  // fp16 stride (halves) for x tile: conflict-free transpose
#define MSTR 68                  // f32 stride (floats) for mask tile

typedef __attribute__((ext_vector_type(8))) _Float16 half8;
typedef __attribute__((ext_vector_type(2))) _Float16 hv2;
typedef __attribute__((ext_vector_type(4))) float f32x4;

// Fused main: grid-stride persistent blocks over d-tiles, double-buffered LDS.
// Per tile: stage x (fp16) + mask (f32) transposed into LDS, G tile via MFMA,
// inner loop h1 = relu(x*w0 + G) packed fp16 -> h2 MFMA -> masked fp32 accum in regs.
// Output: per-block partial [B][K] written with plain stores (no atomics, no memset).
__global__ __launch_bounds__(256, 2) void main_kernel(
    const float* __restrict__ x, const int* __restrict__ mask,
    const float* __restrict__ feat_emb, const float* __restrict__ feat_bias,
    const float* __restrict__ W1, const float* __restrict__ b1,
    const float* __restrict__ W2, const float* __restrict__ b2,
    float* __restrict__ part)
{
    __shared__ __align__(16) _Float16 sGh[2][DTILE * H];     // 2 x 4 KB
    __shared__ __align__(16) _Float16 sXh[2][DTILE * XSTR];  // 2 x 2.125 KB
    __shared__ __align__(16) float    sMf[2][DTILE * MSTR];  // 2 x 4.25 KB

    const int t    = threadIdx.x;
    const int lane = t & 63;
    const int wv   = t >> 6;
    const int g    = lane >> 4;
    const int n    = lane & 15;

    // ---- per-block constant fragments (W1 9KB, W2 8KB: L2-resident) ----
    half8 Bf[4];                      // W2 fragments for h2 MFMA
    #pragma unroll
    for (int s = 0; s < 4; ++s) {
        union { half8 v; _Float16 e[8]; } u;
        #pragma unroll
        for (int j = 0; j < 8; ++j)
            u.e[j] = (_Float16)W2[(s * 32 + g * 8 + j) * K + n];
        Bf[s] = u.v;
    }
    hv2 w0h[4][4];                    // W1 row 0 (x-coefficient), packed fp16 pairs
    #pragma unroll
    for (int s = 0; s < 4; ++s) {
        const float4* wp = (const float4*)&W1[s * 32 + g * 8];
        float4 a0 = wp[0], a1 = wp[1];
        w0h[s][0] = (hv2){(_Float16)a0.x, (_Float16)a0.y};
        w0h[s][1] = (hv2){(_Float16)a0.z, (_Float16)a0.w};
        w0h[s][2] = (hv2){(_Float16)a1.x, (_Float16)a1.y};
        w0h[s][3] = (hv2){(_Float16)a1.z, (_Float16)a1.w};
    }
    half8 bfG[2];                     // extended-W1 B fragments for G MFMA
    #pragma unroll
    for (int cc = 0; cc < 2; ++cc) {
        const int h = (wv * 2 + cc) * 16 + n;
        union { half8 v; _Float16 e[8]; } u;
        #pragma unroll
        for (int j = 0; j < 8; ++j) {
            const int k = g * 8 + j;
            float v;
            if (k < 16)       v = W1[(1 + k) * H + h];
            else if (k == 16) v = W1[17 * H + h];   // feat_bias coefficient row
            else if (k == 17) v = b1[h];            // times 1.0 in A
            else              v = 0.f;
            u.e[j] = (_Float16)v;
        }
        bfG[cc] = u.v;
    }
    const float b2n = b2[n];
    const hv2 zeroh = {(_Float16)0.f, (_Float16)0.f};
    const int moff = wv * 16 + g * 4;
    const int sample = wv * 16 + n;

    // stage one 64x16 x/mask tile: coalesced float4/int4 row reads, transpose to LDS
    auto STAGE = [&](int buf, int tile) {
        const int bb = t >> 2;              // sample row 0..63
        const int dd = (t & 3) * 4;         // 0,4,8,12
        const int dg = tile * DTILE + dd;
        float xv[4], mv[4];
        if (dg + 4 <= D) {
            float4 xx = *(const float4*)&x[(size_t)bb * D + dg];
            int4   mm = *(const int4*)&mask[(size_t)bb * D + dg];
            xv[0] = xx.x; xv[1] = xx.y; xv[2] = xx.z; xv[3] = xx.w;
            mv[0] = (float)mm.x; mv[1] = (float)mm.y; mv[2] = (float)mm.z; mv[3] = (float)mm.w;
        } else {                            // only the final partial tile
            #pragma unroll
            for (int i = 0; i < 4; ++i) {
                const int dgi = dg + i;
                xv[i] = (dgi < D) ? x[(size_t)bb * D + dgi] : 0.f;
                mv[i] = (dgi < D) ? (float)mask[(size_t)bb * D + dgi] : 0.f;
            }
        }
        #pragma unroll
        for (int i = 0; i < 4; ++i) {
            sXh[buf][(dd + i) * XSTR + bb] = (_Float16)xv[i];
            sMf[buf][(dd + i) * MSTR + bb] = mv[i];
        }
    };

    // G tile: A[m=dd][k] = [feat_emb | feat_bias | 1 | 0]
    auto GCOMP = [&](int buf, int tile) {
        const int dA = min(tile * DTILE + n, D - 1);  // OOB rows killed by mask=0
        union { half8 v; _Float16 e[8]; } af;
        if (g < 2) {
            const float4* fe = (const float4*)&feat_emb[(size_t)dA * K + g * 8];
            float4 u0 = fe[0], u1 = fe[1];
            af.e[0] = (_Float16)u0.x; af.e[1] = (_Float16)u0.y;
            af.e[2] = (_Float16)u0.z; af.e[3] = (_Float16)u0.w;
            af.e[4] = (_Float16)u1.x; af.e[5] = (_Float16)u1.y;
            af.e[6] = (_Float16)u1.z; af.e[7] = (_Float16)u1.w;
        } else if (g == 2) {
            af.e[0] = (_Float16)feat_bias[dA];
            af.e[1] = (_Float16)1.f;
            #pragma unroll
            for (int j = 2; j < 8; ++j) af.e[j] = (_Float16)0.f;
        } else {
            #pragma unroll
            for (int j = 0; j < 8; ++j) af.e[j] = (_Float16)0.f;
        }
        #pragma unroll
        for (int cc = 0; cc < 2; ++cc) {
            f32x4 C = {0.f, 0.f, 0.f, 0.f};
            C = __builtin_amdgcn_mfma_f32_16x16x32_f16(af.v, bfG[cc], C, 0, 0, 0);
            #pragma unroll
            for (int r = 0; r < 4; ++r)
                sGh[buf][(g * 4 + r) * H + (wv * 2 + cc) * 16 + n] = (_Float16)C[r];
        }
    };

    f32x4 cacc = {0.f, 0.f, 0.f, 0.f};

    int tt = blockIdx.x;
    STAGE(0, tt);
    GCOMP(0, tt);
    __syncthreads();

    int cur = 0;
    for (; tt < NT_TILES; tt += NPB) {
        const int nxt = tt + NPB;
        if (nxt < NT_TILES) { STAGE(cur ^ 1, nxt); GCOMP(cur ^ 1, nxt); }  // overlap next stage

        hv2 xh[DTILE / 2];
        #pragma unroll
        for (int i = 0; i < DTILE / 2; ++i)
            xh[i] = (hv2){sXh[cur][(2 * i) * XSTR + sample],
                          sXh[cur][(2 * i + 1) * XSTR + sample]};
        const _Float16* gb0 = sGh[cur] + g * 8;

        #pragma unroll
        for (int i = 0; i < DTILE / 2; ++i) {
            const int dd0 = 2 * i, dd1 = 2 * i + 1;
            const hv2 xa = {xh[i].x, xh[i].x};
            const hv2 xb = {xh[i].y, xh[i].y};
            f32x4 c1a = {b2n, b2n, b2n, b2n};
            f32x4 c1b = {b2n, b2n, b2n, b2n};
            #pragma unroll
            for (int s = 0; s < 4; ++s) {
                union GA { half8 v; hv2 p[4]; };
                GA ga, gb, A0, A1;
                ga.v = *(const half8*)(gb0 + dd0 * H + s * 32);  // broadcast ds_read_b128
                gb.v = *(const half8*)(gb0 + dd1 * H + s * 32);
                #pragma unroll
                for (int p = 0; p < 4; ++p) {
                    hv2 h0 = __builtin_elementwise_fma(xa, w0h[s][p], ga.p[p]);
                    hv2 h1 = __builtin_elementwise_fma(xb, w0h[s][p], gb.p[p]);
                    A0.p[p] = __builtin_elementwise_max(h0, zeroh);
                    A1.p[p] = __builtin_elementwise_max(h1, zeroh);
                }
                c1a = __builtin_amdgcn_mfma_f32_16x16x32_f16(A0.v, Bf[s], c1a, 0, 0, 0);
                c1b = __builtin_amdgcn_mfma_f32_16x16x32_f16(A1.v, Bf[s], c1b, 0, 0, 0);
            }
            // mask: float4 broadcast reads, no cvt
            float4 m0 = *(const float4*)&sMf[cur][dd0 * MSTR + moff];
            float4 m1 = *(const float4*)&sMf[cur][dd1 * MSTR + moff];
            cacc[0] = fmaf(m0.x, fmaxf(c1a[0], 0.f), fmaf(m1.x, fmaxf(c1b[0], 0.f), cacc[0]));
            cacc[1] = fmaf(m0.y, fmaxf(c1a[1], 0.f), fmaf(m1.y, fmaxf(c1b[1], 0.f), cacc[1]));
            cacc[2] = fmaf(m0.z, fmaxf(c1a[2], 0.f), fmaf(m1.z, fmaxf(c1b[2], 0.f), cacc[2]));
            cacc[3] = fmaf(m0.w, fmaxf(c1a[3], 0.f), fmaf(m1.w, fmaxf(c1b[3], 0.f), cacc[3]));
        }
        __syncthreads();
        cur ^= 1;
    }

    // per-block partial output: plain stores, no atomics, no init dependency
    float* crep = part + (size_t)blockIdx.x * (B * K);
    #pragma unroll
    for (int r = 0; r < 4; ++r)
        crep[(moff + r) * K + n] = cacc[r];
}

// enc: reduce NPB partials -> c[b], then 16->256->64 MLP. one block per sample.
__global__ __launch_bounds__(256) void partial_enc_kernel(
    const float* __restrict__ part, const float* __restrict__ We1,
    const float* __restrict__ be1, const float* __restrict__ We2,
    const float* __restrict__ be2, float* __restrict__ out)
{
    const int b = blockIdx.x;
    const int t = threadIdx.x;
    __shared__ float sc[K];
    __shared__ float st1[E];
    __shared__ float red[256];

    {
        const int k = t & 15;
        float acc0 = 0.f;
        #pragma unroll 4
        for (int p = t >> 4; p < NPB; p += 16)
            acc0 += part[(size_t)p * (B * K) + b * K + k];
        red[t] = acc0;
    }
    __syncthreads();
    if (t < K) {
        float s2 = 0.f;
        #pragma unroll
        for (int q = 0; q < 16; ++q) s2 += red[q * 16 + t];
        sc[t] = s2;
    }
    __syncthreads();

    {
        float acc = be1[t];
        #pragma unroll
        for (int k = 0; k < K; ++k)
            acc = fmaf(sc[k], We1[k * E + t], acc);
        st1[t] = fmaxf(acc, 0.f);
    }
    __syncthreads();

    const int j = t & 63, seg = t >> 6;
    float acc = 0.f;
    #pragma unroll 4
    for (int e = seg * 64; e < seg * 64 + 64; ++e)
        acc = fmaf(st1[e], We2[e * 64 + j], acc);
    red[t] = acc;
    __syncthreads();

    if (t < 64) {
        float v = red[j] + red[64 + j] + red[128 + j] + red[192 + j] + be2[j];
        if (j < Z) out[b * Z + j] = v;                 // mu
        else       out[B * Z + b * Z + (j - Z)] = v;   // logvar
    }
}

extern "C" void kernel_launch(void* const* d_in, const int* in_sizes, int n_in,
                              void* d_out, int out_size, void* d_ws, size_t ws_size,
                              hipStream_t stream) {
    const float* x         = (const float*)d_in[0];
    const int*   mask      = (const int*)  d_in[1];
    const float* feat_emb  = (const float*)d_in[2];
    const float* feat_bias = (const float*)d_in[3];
    const float* W1        = (const float*)d_in[4];
    const float* b1        = (const float*)d_in[5];
    const float* W2        = (const float*)d_in[6];
    const float* b2        = (const float*)d_in[7];
    const float* We1       = (const float*)d_in[8];
    const float* be1       = (const float*)d_in[9];
    const float* We2       = (const float*)d_in[10];
    const float* be2       = (const float*)d_in[11];

    float* part = (float*)d_ws;   // NPB * B * K * 4 = 2 MB, fully written before read

    main_kernel<<<NPB, 256, 0, stream>>>(
        x, mask, feat_emb, feat_bias, W1, b1, W2, b2, part);
    partial_enc_kernel<<<B, 256, 0, stream>>>(
        part, We1, be1, We2, be2, (float*)d_out);
}

// Round 9
// 108.393 us; speedup vs baseline: 1.0669x; 1.0344x over previous
//
#include <hip/hip_runtime.h>

// Problem constants
#define B 64
#define D 25000
#define K 16
#define H 128
#define E 256
#define Z 32
#define DTILE 16
#define NT_TILES ((D + DTILE - 1) / DTILE)   // 1563
#define NPB 512                  // grid-stride blocks: 2/CU, ~3 tiles each
#define XROW 20                  // halves per sample row of x tile (16 dd + 4 pad), keeps b64 align
#define MROWF 68                 // floats per dd row of mask tile (64 b + 4 pad)

typedef __attribute__((ext_vector_type(8))) _Float16 half8;
typedef __attribute__((ext_vector_type(4))) _Float16 hv4;
typedef __attribute__((ext_vector_type(2))) _Float16 hv2;
typedef __attribute__((ext_vector_type(4))) float f32x4;

// Fused main: grid-stride blocks over d-tiles, double-buffered LDS.
// Wave partition: each wave owns 4 dd rows x all 64 samples (4 m-tiles), so
// G[dd][h] LDS reads are reused across m-tiles: 16 b128/tile/wave,
// no cross-wave redundancy. x staged [b][dd] (aligned b64 reads).
// NOTE: waves own disjoint dd but the SAME (b,k) outputs -> cross-wave LDS
// reduction epilogue before the global store (R6 bug: plain stores raced).
__global__ __launch_bounds__(256, 2) void main_kernel(
    const float* __restrict__ x, const int* __restrict__ mask,
    const float* __restrict__ feat_emb, const float* __restrict__ feat_bias,
    const float* __restrict__ W1, const float* __restrict__ b1,
    const float* __restrict__ W2, const float* __restrict__ b2,
    float* __restrict__ part)
{
    __shared__ __align__(16) _Float16 sGh[2][DTILE * H];     // 2 x 4 KB
    __shared__ __align__(16) _Float16 sXb[2][B * XROW];      // 2 x 2.5 KB  [b][dd]
    __shared__ __align__(16) float    sMf[2][DTILE * MROWF]; // 2 x 4.25 KB [dd][b]
    __shared__ __align__(16) float    sRed[4][B * K];        // 16 KB cross-wave reduce

    const int t    = threadIdx.x;
    const int lane = t & 63;
    const int wv   = t >> 6;
    const int g    = lane >> 4;
    const int n    = lane & 15;

    // ---- per-block constant fragments (W1 9KB, W2 8KB: cache-resident) ----
    half8 Bf[4];                      // W2 fragments for h2 MFMA
    #pragma unroll
    for (int s = 0; s < 4; ++s) {
        union { half8 v; _Float16 e[8]; } u;
        #pragma unroll
        for (int j = 0; j < 8; ++j)
            u.e[j] = (_Float16)W2[(s * 32 + g * 8 + j) * K + n];
        Bf[s] = u.v;
    }
    hv2 w0h[4][4];                    // W1 row 0 (x-coefficient), packed fp16 pairs
    #pragma unroll
    for (int s = 0; s < 4; ++s) {
        const float4* wp = (const float4*)&W1[s * 32 + g * 8];
        float4 a0 = wp[0], a1 = wp[1];
        w0h[s][0] = (hv2){(_Float16)a0.x, (_Float16)a0.y};
        w0h[s][1] = (hv2){(_Float16)a0.z, (_Float16)a0.w};
        w0h[s][2] = (hv2){(_Float16)a1.x, (_Float16)a1.y};
        w0h[s][3] = (hv2){(_Float16)a1.z, (_Float16)a1.w};
    }
    half8 bfG[2];                     // extended-W1 B fragments for G MFMA
    #pragma unroll
    for (int cc = 0; cc < 2; ++cc) {
        const int h = (wv * 2 + cc) * 16 + n;
        union { half8 v; _Float16 e[8]; } u;
        #pragma unroll
        for (int j = 0; j < 8; ++j) {
            const int k = g * 8 + j;
            float v;
            if (k < 16)       v = W1[(1 + k) * H + h];
            else if (k == 16) v = W1[17 * H + h];   // feat_bias coefficient row
            else if (k == 17) v = b1[h];            // times 1.0 in A
            else              v = 0.f;
            u.e[j] = (_Float16)v;
        }
        bfG[cc] = u.v;
    }
    const float b2n = b2[n];
    const hv2 zeroh = {(_Float16)0.f, (_Float16)0.f};
    const int ddb = wv * 4;           // this wave's dd base

    // stage one 64x16 x/mask tile: coalesced float4/int4 row reads
    auto STAGE = [&](int buf, int tile) {
        const int bb = t >> 2;              // sample row 0..63
        const int dd = (t & 3) * 4;         // 0,4,8,12
        const int dg = tile * DTILE + dd;
        float xv[4], mv[4];
        if (dg + 4 <= D) {
            float4 xx = *(const float4*)&x[(size_t)bb * D + dg];
            int4   mm = *(const int4*)&mask[(size_t)bb * D + dg];
            xv[0] = xx.x; xv[1] = xx.y; xv[2] = xx.z; xv[3] = xx.w;
            mv[0] = (float)mm.x; mv[1] = (float)mm.y; mv[2] = (float)mm.z; mv[3] = (float)mm.w;
        } else {                            // only the final partial tile
            #pragma unroll
            for (int i = 0; i < 4; ++i) {
                const int dgi = dg + i;
                xv[i] = (dgi < D) ? x[(size_t)bb * D + dgi] : 0.f;
                mv[i] = (dgi < D) ? (float)mask[(size_t)bb * D + dgi] : 0.f;
            }
        }
        hv4 xp = {(_Float16)xv[0], (_Float16)xv[1], (_Float16)xv[2], (_Float16)xv[3]};
        *(hv4*)&sXb[buf][bb * XROW + dd] = xp;    // one aligned ds_write_b64
        #pragma unroll
        for (int i = 0; i < 4; ++i)
            sMf[buf][(dd + i) * MROWF + bb] = mv[i];   // 2-way max on writes (free)
    };

    // G tile via MFMA: A[m=dd][k] = [feat_emb | feat_bias | 1 | 0]
    auto GCOMP = [&](int buf, int tile) {
        const int dA = min(tile * DTILE + n, D - 1);  // OOB rows killed by mask=0
        union { half8 v; _Float16 e[8]; } af;
        if (g < 2) {
            const float4* fe = (const float4*)&feat_emb[(size_t)dA * K + g * 8];
            float4 u0 = fe[0], u1 = fe[1];
            af.e[0] = (_Float16)u0.x; af.e[1] = (_Float16)u0.y;
            af.e[2] = (_Float16)u0.z; af.e[3] = (_Float16)u0.w;
            af.e[4] = (_Float16)u1.x; af.e[5] = (_Float16)u1.y;
            af.e[6] = (_Float16)u1.z; af.e[7] = (_Float16)u1.w;
        } else if (g == 2) {
            af.e[0] = (_Float16)feat_bias[dA];
            af.e[1] = (_Float16)1.f;
            #pragma unroll
            for (int j = 2; j < 8; ++j) af.e[j] = (_Float16)0.f;
        } else {
            #pragma unroll
            for (int j = 0; j < 8; ++j) af.e[j] = (_Float16)0.f;
        }
        #pragma unroll
        for (int cc = 0; cc < 2; ++cc) {
            f32x4 C = {0.f, 0.f, 0.f, 0.f};
            C = __builtin_amdgcn_mfma_f32_16x16x32_f16(af.v, bfG[cc], C, 0, 0, 0);
            #pragma unroll
            for (int r = 0; r < 4; ++r)
                sGh[buf][(g * 4 + r) * H + (wv * 2 + cc) * 16 + n] = (_Float16)C[r];
        }
    };

    f32x4 cacc[4] = {{0.f,0.f,0.f,0.f},{0.f,0.f,0.f,0.f},{0.f,0.f,0.f,0.f},{0.f,0.f,0.f,0.f}};

    int tt = blockIdx.x;
    STAGE(0, tt);
    GCOMP(0, tt);
    __syncthreads();

    int cur = 0;
    for (; tt < NT_TILES; tt += NPB) {
        const int nxt = tt + NPB;
        if (nxt < NT_TILES) { STAGE(cur ^ 1, nxt); GCOMP(cur ^ 1, nxt); }  // overlap next stage

        // x for this wave: 4 m-tiles, each a b64 of x[m*16+n][ddb..ddb+3]
        hv4 xq[4];
        #pragma unroll
        for (int m = 0; m < 4; ++m)
            xq[m] = *(const hv4*)&sXb[cur][(m * 16 + n) * XROW + ddb];

        #pragma unroll
        for (int i = 0; i < 4; ++i) {
            const int dd = ddb + i;
            half8 Gv[4];                              // G[dd][h-slice], reused over 4 m-tiles
            #pragma unroll
            for (int s = 0; s < 4; ++s)
                Gv[s] = *(const half8*)&sGh[cur][dd * H + s * 32 + g * 8];  // broadcast b128
            #pragma unroll
            for (int m = 0; m < 4; ++m) {
                const _Float16 xs = xq[m][i];
                const hv2 xx = {xs, xs};
                f32x4 c1 = {b2n, b2n, b2n, b2n};
                #pragma unroll
                for (int s = 0; s < 4; ++s) {
                    union GA { half8 v; hv2 p[4]; };
                    GA gg, A0;
                    gg.v = Gv[s];
                    #pragma unroll
                    for (int p = 0; p < 4; ++p) {
                        hv2 h0 = __builtin_elementwise_fma(xx, w0h[s][p], gg.p[p]);
                        A0.p[p] = __builtin_elementwise_max(h0, zeroh);
                    }
                    c1 = __builtin_amdgcn_mfma_f32_16x16x32_f16(A0.v, Bf[s], c1, 0, 0, 0);
                }
                // mask rows m*16+g*4..+3 for this dd: one broadcast b128
                float4 mk = *(const float4*)&sMf[cur][dd * MROWF + m * 16 + g * 4];
                cacc[m][0] = fmaf(mk.x, fmaxf(c1[0], 0.f), cacc[m][0]);
                cacc[m][1] = fmaf(mk.y, fmaxf(c1[1], 0.f), cacc[m][1]);
                cacc[m][2] = fmaf(mk.z, fmaxf(c1[2], 0.f), cacc[m][2]);
                cacc[m][3] = fmaf(mk.w, fmaxf(c1[3], 0.f), cacc[m][3]);
            }
        }
        __syncthreads();
        cur ^= 1;
    }

    // ---- cross-wave reduction: 4 waves hold partial sums for the SAME (b,k) ----
    #pragma unroll
    for (int m = 0; m < 4; ++m)
        #pragma unroll
        for (int r = 0; r < 4; ++r)
            sRed[wv][(m * 16 + g * 4 + r) * K + n] = cacc[m][r];
    __syncthreads();
    // each thread sums the 4 wave slots for 4 flat (b,k) outputs; coalesced store
    #pragma unroll
    for (int q = 0; q < 4; ++q) {
        const int o = t + q * 256;                 // o = b*K + k
        const float v = sRed[0][o] + sRed[1][o] + sRed[2][o] + sRed[3][o];
        part[(size_t)(o >> 4) * (NPB * K) + (size_t)blockIdx.x * K + (o & 15)] = v;
    }
}

// enc: reduce NPB partials -> c[b] (fully coalesced stream), then 16->256->64 MLP.
__global__ __launch_bounds__(256) void partial_enc_kernel(
    const float* __restrict__ part, const float* __restrict__ We1,
    const float* __restrict__ be1, const float* __restrict__ We2,
    const float* __restrict__ be2, float* __restrict__ out)
{
    const int b = blockIdx.x;
    const int t = threadIdx.x;
    __shared__ float sc[K];
    __shared__ float st1[E];
    __shared__ float red[256];

    {
        // part[b] is NPB*K contiguous floats; thread t owns k = t&15 across p = (t>>4)+16i
        const float* pb = part + (size_t)b * (NPB * K);
        float acc0 = 0.f;
        #pragma unroll 8
        for (int i = 0; i < (NPB * K) / 256; ++i)
            acc0 += pb[t + i * 256];
        red[t] = acc0;
    }
    __syncthreads();
    if (t < K) {
        float s2 = 0.f;
        #pragma unroll
        for (int q = 0; q < 16; ++q) s2 += red[q * 16 + t];
        sc[t] = s2;
    }
    __syncthreads();

    {
        float acc = be1[t];
        #pragma unroll
        for (int k = 0; k < K; ++k)
            acc = fmaf(sc[k], We1[k * E + t], acc);
        st1[t] = fmaxf(acc, 0.f);
    }
    __syncthreads();

    const int j = t & 63, seg = t >> 6;
    float acc = 0.f;
    #pragma unroll 4
    for (int e = seg * 64; e < seg * 64 + 64; ++e)
        acc = fmaf(st1[e], We2[e * 64 + j], acc);
    red[t] = acc;
    __syncthreads();

    if (t < 64) {
        float v = red[j] + red[64 + j] + red[128 + j] + red[192 + j] + be2[j];
        if (j < Z) out[b * Z + j] = v;                 // mu
        else       out[B * Z + b * Z + (j - Z)] = v;   // logvar
    }
}

extern "C" void kernel_launch(void* const* d_in, const int* in_sizes, int n_in,
                              void* d_out, int out_size, void* d_ws, size_t ws_size,
                              hipStream_t stream) {
    const float* x         = (const float*)d_in[0];
    const int*   mask      = (const int*)  d_in[1];
    const float* feat_emb  = (const float*)d_in[2];
    const float* feat_bias = (const float*)d_in[3];
    const float* W1        = (const float*)d_in[4];
    const float* b1        = (const float*)d_in[5];
    const float* W2        = (const float*)d_in[6];
    const float* b2        = (const float*)d_in[7];
    const float* We1       = (const float*)d_in[8];
    const float* be1       = (const float*)d_in[9];
    const float* We2       = (const float*)d_in[10];
    const float* be2       = (const float*)d_in[11];

    float* part = (float*)d_ws;   // B * NPB * K * 4 = 2 MB, fully written before read

    main_kernel<<<NPB, 256, 0, stream>>>(
        x, mask, feat_emb, feat_bias, W1, b1, W2, b2, part);
    partial_enc_kernel<<<B, 256, 0, stream>>>(
        part, We1, be1, We2, be2, (float*)d_out);
}